// Round 14
// baseline (1195.580 us; speedup 1.0000x reference)
//
#include <hip/hip_runtime.h>
#include <hip/hip_bf16.h>
#include <cstdint>
#include <cstddef>

#define HD 128

typedef __bf16    bf16x8 __attribute__((ext_vector_type(8)));
typedef float     f32x4  __attribute__((ext_vector_type(4)));
typedef _Float16  h2     __attribute__((ext_vector_type(2)));
typedef _Float16  h8     __attribute__((ext_vector_type(8)));

#if defined(__has_builtin)
#if __has_builtin(__builtin_amdgcn_fdot2)
#define HAVE_FDOT2 1
#endif
#if __has_builtin(__builtin_amdgcn_rcpf)
#define HAVE_RCPF 1
#endif
#endif

__device__ __forceinline__ float fdot2f(h2 a, h2 b, float c) {
#ifdef HAVE_FDOT2
    return __builtin_amdgcn_fdot2(a, b, c, false);
#else
    return c + (float)a[0]*(float)b[0] + (float)a[1]*(float)b[1];
#endif
}

__device__ __forceinline__ float silu_f(float v) {
#ifdef HAVE_RCPF
    return v * __builtin_amdgcn_rcpf(1.f + __expf(-v));
#else
    return v / (1.f + __expf(-v));
#endif
}

// Swizzled byte offset inside a 4KB 16-row slice (256B rows): chunk ^= row.
__device__ __forceinline__ int swz(int r, int byteInRow) {
    int chunk = (byteInRow >> 4) ^ (r & 15);
    return r * 256 + (chunk << 4) + (byteInRow & 15);
}

// ============ barrier-free wave-local residual blocks ============
// Block = 512 thr = 8 waves; wave owns 16 rows x 128 cols; private 4KB LDS slice.
// All h/carry restaging is intra-wave -> NO __syncthreads anywhere.

// stage wave's 16 rows of f32 x as bf16 into its slice
__device__ __forceinline__ void stage16(const float* __restrict__ x, char* sl,
                                        int gr0, int nrows, int lane) {
    #pragma unroll
    for (int i = 0; i < 4; ++i) {
        const int flat = i * 64 + lane;
        const int row = flat >> 4, q = flat & 15;
        const int gr = gr0 + row;
        float4 a = {0,0,0,0}, b = {0,0,0,0};
        if (gr < nrows) {
            const float4* p = (const float4*)(x + (size_t)gr * HD + q * 8);
            a = p[0]; b = p[1];
        }
        bf16x8 v;
        v[0]=(__bf16)a.x; v[1]=(__bf16)a.y; v[2]=(__bf16)a.z; v[3]=(__bf16)a.w;
        v[4]=(__bf16)b.x; v[5]=(__bf16)b.y; v[6]=(__bf16)b.z; v[7]=(__bf16)b.w;
        *(bf16x8*)(sl + swz(row, q * 16)) = v;
    }
}

// acc[n] = (slice[16x128] @ W[128x128]) + bias ; W from global in fragment layout
// (wt[n][kk][lane][e]); A-frags from the wave's own slice.
__device__ __forceinline__ void mm16(const char* sl, const __bf16* __restrict__ wf,
                                     const float* __restrict__ bias,
                                     int crow, int kgrp, f32x4 acc[8]) {
    const int lane = crow + kgrp * 16;
    bf16x8 afr[4];
    #pragma unroll
    for (int kk = 0; kk < 4; ++kk)
        afr[kk] = *(const bf16x8*)(sl + swz(crow, kk * 64 + kgrp * 16));
    #pragma unroll
    for (int n = 0; n < 8; ++n) {
        const float bv = bias[n * 16 + crow];
        f32x4 t = {bv, bv, bv, bv};
        acc[n] = t;
        #pragma unroll
        for (int kk = 0; kk < 4; ++kk) {
            const bf16x8 b = *(const bf16x8*)(wf + (size_t)(((n * 4 + kk) * 64) + lane) * 8);
            acc[n] = __builtin_amdgcn_mfma_f32_16x16x32_bf16(afr[kk], b, acc[n], 0, 0, 0);
        }
    }
}

// write silu(acc) as bf16 h-tile into own slice (C/D layout: row=kgrp*4+rg, col=n*16+crow)
__device__ __forceinline__ void hwrite16(char* sl, const f32x4 acc[8], int crow, int kgrp) {
    #pragma unroll
    for (int n = 0; n < 8; ++n)
        #pragma unroll
        for (int rg = 0; rg < 4; ++rg)
            *(__bf16*)(sl + swz(kgrp * 4 + rg, (n * 16 + crow) * 2)) =
                (__bf16)silu_f(acc[n][rg]);
}

// write bf16(carry) into own slice
__device__ __forceinline__ void cwrite16(char* sl, const float carry[32], int crow, int kgrp) {
    #pragma unroll
    for (int n = 0; n < 8; ++n)
        #pragma unroll
        for (int rg = 0; rg < 4; ++rg)
            *(__bf16*)(sl + swz(kgrp * 4 + rg, (n * 16 + crow) * 2)) = (__bf16)carry[n * 4 + rg];
}

// ---- dual residual: out1 = bf16(x + mlpA(x)), out2 = bf16(x + mlpB(x)) ----
__global__ __launch_bounds__(512, 3) void resid_dual_kernel(
    const float* __restrict__ x,
    const __bf16* __restrict__ wtA, const float* __restrict__ bA,
    const __bf16* __restrict__ wtB, const float* __restrict__ bB,
    __bf16* __restrict__ out1, __bf16* __restrict__ out2, int nrows)
{
    __shared__ char lds[32768];
    const int tid = threadIdx.x, lane = tid & 63, wv = tid >> 6;
    const int crow = lane & 15, kgrp = lane >> 4;
    char* sl = lds + wv * 4096;
    const int gr0 = blockIdx.x * 128 + wv * 16;

    stage16(x, sl, gr0, nrows, lane);
    float xe[32];
    #pragma unroll
    for (int n = 0; n < 8; ++n)
        #pragma unroll
        for (int rg = 0; rg < 4; ++rg) {
            const int gr = gr0 + kgrp * 4 + rg;
            xe[n * 4 + rg] = (gr < nrows) ? x[(size_t)gr * HD + n * 16 + crow] : 0.f;
        }

    f32x4 acc[8];
    // A0: slice(x) -> h
    mm16(sl, wtA, bA, crow, kgrp, acc);
    hwrite16(sl, acc, crow, kgrp);
    // A1: h -> out1; restore x into slice from xe
    mm16(sl, wtA + 16384, bA + HD, crow, kgrp, acc);
    #pragma unroll
    for (int n = 0; n < 8; ++n)
        #pragma unroll
        for (int rg = 0; rg < 4; ++rg) {
            const int gr = gr0 + kgrp * 4 + rg;
            if (gr < nrows)
                out1[(size_t)gr * HD + n * 16 + crow] =
                    (__bf16)(xe[n * 4 + rg] + silu_f(acc[n][rg]));
        }
    cwrite16(sl, xe, crow, kgrp);
    // B0: slice(x) -> h
    mm16(sl, wtB, bB, crow, kgrp, acc);
    hwrite16(sl, acc, crow, kgrp);
    // B1: h -> out2
    mm16(sl, wtB + 16384, bB + HD, crow, kgrp, acc);
    #pragma unroll
    for (int n = 0; n < 8; ++n)
        #pragma unroll
        for (int rg = 0; rg < 4; ++rg) {
            const int gr = gr0 + kgrp * 4 + rg;
            if (gr < nrows)
                out2[(size_t)gr * HD + n * 16 + crow] =
                    (__bf16)(xe[n * 4 + rg] + silu_f(acc[n][rg]));
        }
}

// ---- fused 4-block chain: y = post + R_D(R_C(mid ⊙ R_B(R_A(x)))) ----
__global__ __launch_bounds__(512, 3) void chain4_kernel(
    const float* __restrict__ x, const __bf16* __restrict__ mid,
    const __bf16* __restrict__ wA, const float* __restrict__ bA,
    const __bf16* __restrict__ wB, const float* __restrict__ bB,
    const __bf16* __restrict__ wC, const float* __restrict__ bC,
    const __bf16* __restrict__ wD, const float* __restrict__ bD,
    const float* __restrict__ post, float* __restrict__ y, int nrows)
{
    __shared__ char lds[32768];
    const int tid = threadIdx.x, lane = tid & 63, wv = tid >> 6;
    const int crow = lane & 15, kgrp = lane >> 4;
    char* sl = lds + wv * 4096;
    const int gr0 = blockIdx.x * 128 + wv * 16;

    stage16(x, sl, gr0, nrows, lane);
    float carry[32];
    #pragma unroll
    for (int n = 0; n < 8; ++n)
        #pragma unroll
        for (int rg = 0; rg < 4; ++rg) {
            const int gr = gr0 + kgrp * 4 + rg;
            carry[n * 4 + rg] = (gr < nrows) ? x[(size_t)gr * HD + n * 16 + crow] : 0.f;
        }

    f32x4 acc[8];
    // A
    mm16(sl, wA, bA, crow, kgrp, acc);
    hwrite16(sl, acc, crow, kgrp);
    mm16(sl, wA + 16384, bA + HD, crow, kgrp, acc);
    #pragma unroll
    for (int n = 0; n < 8; ++n)
        #pragma unroll
        for (int rg = 0; rg < 4; ++rg) carry[n * 4 + rg] += silu_f(acc[n][rg]);
    cwrite16(sl, carry, crow, kgrp);
    // B (+ mid)
    mm16(sl, wB, bB, crow, kgrp, acc);
    hwrite16(sl, acc, crow, kgrp);
    mm16(sl, wB + 16384, bB + HD, crow, kgrp, acc);
    #pragma unroll
    for (int n = 0; n < 8; ++n)
        #pragma unroll
        for (int rg = 0; rg < 4; ++rg) {
            const int gr = gr0 + kgrp * 4 + rg;
            const float m = (gr < nrows) ? (float)mid[(size_t)gr * HD + n * 16 + crow] : 0.f;
            carry[n * 4 + rg] = (carry[n * 4 + rg] + silu_f(acc[n][rg])) * m;
        }
    cwrite16(sl, carry, crow, kgrp);
    // C
    mm16(sl, wC, bC, crow, kgrp, acc);
    hwrite16(sl, acc, crow, kgrp);
    mm16(sl, wC + 16384, bC + HD, crow, kgrp, acc);
    #pragma unroll
    for (int n = 0; n < 8; ++n)
        #pragma unroll
        for (int rg = 0; rg < 4; ++rg) carry[n * 4 + rg] += silu_f(acc[n][rg]);
    cwrite16(sl, carry, crow, kgrp);
    // D + epilogue
    mm16(sl, wD, bD, crow, kgrp, acc);
    hwrite16(sl, acc, crow, kgrp);
    mm16(sl, wD + 16384, bD + HD, crow, kgrp, acc);
    #pragma unroll
    for (int n = 0; n < 8; ++n)
        #pragma unroll
        for (int rg = 0; rg < 4; ++rg) {
            const int gr = gr0 + kgrp * 4 + rg;
            if (gr < nrows) {
                const int cc = n * 16 + crow;
                y[(size_t)gr * HD + cc] =
                    carry[n * 4 + rg] + silu_f(acc[n][rg]) + post[(size_t)gr * HD + cc];
            }
        }
}

// ---- fused 3-block graph chain: out = R_C(R_B(R_A(x))) ----
__global__ __launch_bounds__(512, 3) void chain3_kernel(
    const float* __restrict__ x,
    const __bf16* __restrict__ wA, const float* __restrict__ bA,
    const __bf16* __restrict__ wB, const float* __restrict__ bB,
    const __bf16* __restrict__ wC, const float* __restrict__ bC,
    float* __restrict__ y, int nrows)
{
    __shared__ char lds[32768];
    const int tid = threadIdx.x, lane = tid & 63, wv = tid >> 6;
    const int crow = lane & 15, kgrp = lane >> 4;
    char* sl = lds + wv * 4096;
    const int gr0 = blockIdx.x * 128 + wv * 16;

    stage16(x, sl, gr0, nrows, lane);
    float carry[32];
    #pragma unroll
    for (int n = 0; n < 8; ++n)
        #pragma unroll
        for (int rg = 0; rg < 4; ++rg) {
            const int gr = gr0 + kgrp * 4 + rg;
            carry[n * 4 + rg] = (gr < nrows) ? x[(size_t)gr * HD + n * 16 + crow] : 0.f;
        }

    f32x4 acc[8];
    mm16(sl, wA, bA, crow, kgrp, acc);
    hwrite16(sl, acc, crow, kgrp);
    mm16(sl, wA + 16384, bA + HD, crow, kgrp, acc);
    #pragma unroll
    for (int n = 0; n < 8; ++n)
        #pragma unroll
        for (int rg = 0; rg < 4; ++rg) carry[n * 4 + rg] += silu_f(acc[n][rg]);
    cwrite16(sl, carry, crow, kgrp);
    mm16(sl, wB, bB, crow, kgrp, acc);
    hwrite16(sl, acc, crow, kgrp);
    mm16(sl, wB + 16384, bB + HD, crow, kgrp, acc);
    #pragma unroll
    for (int n = 0; n < 8; ++n)
        #pragma unroll
        for (int rg = 0; rg < 4; ++rg) carry[n * 4 + rg] += silu_f(acc[n][rg]);
    cwrite16(sl, carry, crow, kgrp);
    mm16(sl, wC, bC, crow, kgrp, acc);
    hwrite16(sl, acc, crow, kgrp);
    mm16(sl, wC + 16384, bC + HD, crow, kgrp, acc);
    #pragma unroll
    for (int n = 0; n < 8; ++n)
        #pragma unroll
        for (int rg = 0; rg < 4; ++rg) {
            const int gr = gr0 + kgrp * 4 + rg;
            if (gr < nrows)
                y[(size_t)gr * HD + n * 16 + crow] = carry[n * 4 + rg] + silu_f(acc[n][rg]);
        }
}

// ---- CSR build ----
__global__ __launch_bounds__(256) void hist_kernel(const int* __restrict__ erow, int* __restrict__ cnt, int E) {
    int i = blockIdx.x * blockDim.x + threadIdx.x;
    const int stride = gridDim.x * blockDim.x;
    for (; i < E; i += stride) atomicAdd(&cnt[erow[i]], 1);
}

__global__ __launch_bounds__(256) void scan1_kernel(const int* __restrict__ cnt, int* __restrict__ part, int n) {
    __shared__ int red[256];
    const int base = blockIdx.x * 1024;
    int s = 0;
    for (int i = threadIdx.x; i < 1024; i += 256) {
        const int idx = base + i;
        s += (idx < n) ? cnt[idx] : 0;
    }
    red[threadIdx.x] = s; __syncthreads();
    for (int o = 128; o > 0; o >>= 1) {
        if (threadIdx.x < o) red[threadIdx.x] += red[threadIdx.x + o];
        __syncthreads();
    }
    if (threadIdx.x == 0) part[blockIdx.x] = red[0];
}

__global__ __launch_bounds__(256) void scan2_kernel(int* __restrict__ part, int nb,
                                                    int* __restrict__ rowptr, int n) {
    __shared__ int sh[257];
    const int tid = threadIdx.x;
    int a[4]; int s = 0;
    #pragma unroll
    for (int q = 0; q < 4; ++q) {
        const int i = tid*4 + q;
        a[q] = (i < nb) ? part[i] : 0;
        s += a[q];
    }
    sh[tid + 1] = s; __syncthreads();
    if (tid == 0) {
        sh[0] = 0;
        int run = 0;
        for (int i = 1; i <= 256; ++i) { run += sh[i]; sh[i] = run; }
    }
    __syncthreads();
    int off = sh[tid];
    #pragma unroll
    for (int q = 0; q < 4; ++q) {
        const int i = tid*4 + q;
        if (i < nb) part[i] = off;
        off += a[q];
    }
    if (tid == 255) rowptr[n] = off;
}

__global__ __launch_bounds__(256) void scan3_kernel(const int* __restrict__ cnt, const int* __restrict__ part,
                                                    int* __restrict__ rowptr, int n) {
    __shared__ int sc[257];
    const int base = blockIdx.x * 1024;
    const int i0 = base + threadIdx.x * 4;
    int v[4]; int s = 0;
    #pragma unroll
    for (int q = 0; q < 4; ++q) {
        const int idx = i0 + q;
        v[q] = (idx < n) ? cnt[idx] : 0;
        s += v[q];
    }
    sc[threadIdx.x + 1] = s; __syncthreads();
    if (threadIdx.x == 0) {
        int run = 0;
        for (int i = 0; i < 256; ++i) { const int t = sc[i + 1]; sc[i + 1] = run; run += t; }
    }
    __syncthreads();
    int off = part[blockIdx.x] + sc[threadIdx.x + 1];
    #pragma unroll
    for (int q = 0; q < 4; ++q) {
        const int idx = i0 + q;
        if (idx < n) rowptr[idx] = off;
        off += v[q];
    }
}

// scatter + reorder fused: csr_col[p] = ecol[i], csr_ef[p] = fp16(ef[i] * cs[i])
__global__ __launch_bounds__(256) void scatter_reorder_kernel(
    const int* __restrict__ erow, const int* __restrict__ ecol,
    const float* __restrict__ ef, const float* __restrict__ cs,
    const int* __restrict__ rowptr, int* __restrict__ cursor,
    int* __restrict__ csr_col, _Float16* __restrict__ csr_ef, int E)
{
    int i = blockIdx.x * blockDim.x + threadIdx.x;
    const int stride = gridDim.x * blockDim.x;
    for (; i < E; i += stride) {
        const int r = erow[i];
        const int p = rowptr[r] + atomicAdd(&cursor[r], 1);
        csr_col[p] = ecol[i];
        const float c = cs[i];
        const float4* ep = (const float4*)(ef + (size_t)i * 16);
        const float4 e0 = ep[0], e1 = ep[1], e2 = ep[2], e3 = ep[3];
        h8 v0, v1;
        v0[0]=(_Float16)(e0.x*c); v0[1]=(_Float16)(e0.y*c); v0[2]=(_Float16)(e0.z*c); v0[3]=(_Float16)(e0.w*c);
        v0[4]=(_Float16)(e1.x*c); v0[5]=(_Float16)(e1.y*c); v0[6]=(_Float16)(e1.z*c); v0[7]=(_Float16)(e1.w*c);
        v1[0]=(_Float16)(e2.x*c); v1[1]=(_Float16)(e2.y*c); v1[2]=(_Float16)(e2.z*c); v1[3]=(_Float16)(e2.w*c);
        v1[4]=(_Float16)(e3.x*c); v1[5]=(_Float16)(e3.y*c); v1[6]=(_Float16)(e3.z*c); v1[7]=(_Float16)(e3.w*c);
        h8* dst = (h8*)(csr_ef + (size_t)p * 16);
        dst[0] = v0; dst[1] = v1;
    }
}

// elin f32 [16][128] -> fp16 (per layer)
__global__ __launch_bounds__(256) void elin16_kernel(const float* __restrict__ elin,
                                                     _Float16* __restrict__ out, int total) {
    const int i = blockIdx.x * 256 + threadIdx.x;
    if (i < total) out[i] = (_Float16)elin[i];
}

__device__ __forceinline__ float bfu_lo(uint32_t u) { return __uint_as_float(u << 16); }
__device__ __forceinline__ float bfu_hi(uint32_t u) { return __uint_as_float(u & 0xffff0000u); }

__device__ __forceinline__ void edge_dot(const h8 a0, const h8 a1,
                                         const h2 w0[8], const h2 w1[8],
                                         float& f0, float& f1) {
    #pragma unroll
    for (int kk = 0; kk < 4; ++kk) {
        h2 p = {a0[2*kk], a0[2*kk+1]};
        f0 = fdot2f(p, w0[kk], f0);
        f1 = fdot2f(p, w1[kk], f1);
    }
    #pragma unroll
    for (int kk = 0; kk < 4; ++kk) {
        h2 p = {a1[2*kk], a1[2*kk+1]};
        f0 = fdot2f(p, w0[4+kk], f0);
        f1 = fdot2f(p, w1[4+kk], f1);
    }
}

// ---- CSR gather conv, wave-per-node: lane handles cols (2l, 2l+1); unroll-8 gathers ----
__global__ __launch_bounds__(256) void conv_kernel(
    const _Float16* __restrict__ csr_ef, const int* __restrict__ csr_col,
    const _Float16* __restrict__ elin16, const int* __restrict__ rowptr,
    const __bf16* __restrict__ sdst, const float* __restrict__ Cn,
    float* __restrict__ conv, int nnodes)
{
    const int wv   = __builtin_amdgcn_readfirstlane(threadIdx.x >> 6);
    const int lane = threadIdx.x & 63;
    const int v = blockIdx.x * 4 + wv;
    if (v >= nnodes) return;
    const int j0 = lane * 2;

    h2 w0[8], w1[8];
    #pragma unroll
    for (int kk = 0; kk < 8; ++kk) {
        w0[kk][0] = elin16[(2*kk)   * HD + j0];
        w0[kk][1] = elin16[(2*kk+1) * HD + j0];
        w1[kk][0] = elin16[(2*kk)   * HD + j0 + 1];
        w1[kk][1] = elin16[(2*kk+1) * HD + j0 + 1];
    }

    const uint16_t* sd = (const uint16_t*)sdst;
    const int beg = rowptr[v], end = rowptr[v + 1];
    float acc0 = 0.f, acc1 = 0.f;
    int t = beg;
    for (; t + 8 <= end; t += 8) {
        int c[8];
        #pragma unroll
        for (int q = 0; q < 8; ++q) c[q] = csr_col[t + q];
        uint32_t u[8];
        #pragma unroll
        for (int q = 0; q < 8; ++q)
            u[q] = *(const uint32_t*)(sd + (size_t)c[q] * HD + j0);
        #pragma unroll
        for (int q = 0; q < 8; ++q) {
            const h8* ep = (const h8*)(csr_ef + (size_t)(t + q) * 16);
            const h8 a0 = ep[0], a1 = ep[1];
            float f0 = 0.f, f1 = 0.f;
            edge_dot(a0, a1, w0, w1, f0, f1);
            acc0 = fmaf(bfu_lo(u[q]), f0, acc0);
            acc1 = fmaf(bfu_hi(u[q]), f1, acc1);
        }
    }
    for (; t + 2 <= end; t += 2) {
        int c[2];
        c[0] = csr_col[t]; c[1] = csr_col[t + 1];
        uint32_t u[2];
        u[0] = *(const uint32_t*)(sd + (size_t)c[0] * HD + j0);
        u[1] = *(const uint32_t*)(sd + (size_t)c[1] * HD + j0);
        #pragma unroll
        for (int q = 0; q < 2; ++q) {
            const h8* ep = (const h8*)(csr_ef + (size_t)(t + q) * 16);
            const h8 a0 = ep[0], a1 = ep[1];
            float f0 = 0.f, f1 = 0.f;
            edge_dot(a0, a1, w0, w1, f0, f1);
            acc0 = fmaf(bfu_lo(u[q]), f0, acc0);
            acc1 = fmaf(bfu_hi(u[q]), f1, acc1);
        }
    }
    if (t < end) {
        const int c = csr_col[t];
        const uint32_t u = *(const uint32_t*)(sd + (size_t)c * HD + j0);
        const h8* ep = (const h8*)(csr_ef + (size_t)t * 16);
        const h8 a0 = ep[0], a1 = ep[1];
        float f0 = 0.f, f1 = 0.f;
        edge_dot(a0, a1, w0, w1, f0, f1);
        acc0 = fmaf(bfu_lo(u), f0, acc0);
        acc1 = fmaf(bfu_hi(u), f1, acc1);
    }
    const float cn = Cn[v];
    float2 out = {acc0 * cn, acc1 * cn};
    *(float2*)(conv + (size_t)v * HD + j0) = out;
}

// sorted segment-sum pooling
__global__ __launch_bounds__(256) void pool_kernel(
    const float* __restrict__ s, const int* __restrict__ bidx,
    float* __restrict__ g, int n)
{
    const int slot = threadIdx.x >> 5;
    const int jc   = (threadIdx.x & 31) * 4;
    const int base = blockIdx.x * 256;
    if (base >= n) return;
    const int end = (base + 256 < n) ? base + 256 : n;
    float4 acc = {0,0,0,0};
    int cur = -1;
    for (int i = base + slot; i < end; i += 8) {
        const int b = bidx[i];
        if (b != cur) {
            if (cur >= 0) {
                atomicAdd(g + (size_t)cur*HD + jc + 0, acc.x);
                atomicAdd(g + (size_t)cur*HD + jc + 1, acc.y);
                atomicAdd(g + (size_t)cur*HD + jc + 2, acc.z);
                atomicAdd(g + (size_t)cur*HD + jc + 3, acc.w);
            }
            acc = {0,0,0,0};
            cur = b;
        }
        const float4 v = *(const float4*)(s + (size_t)i*HD + jc);
        acc.x += v.x; acc.y += v.y; acc.z += v.z; acc.w += v.w;
    }
    if (cur >= 0) {
        atomicAdd(g + (size_t)cur*HD + jc + 0, acc.x);
        atomicAdd(g + (size_t)cur*HD + jc + 1, acc.y);
        atomicAdd(g + (size_t)cur*HD + jc + 2, acc.z);
        atomicAdd(g + (size_t)cur*HD + jc + 3, acc.w);
    }
}

// W -> 16x16 MFMA B-fragment layout:
// wt[mat][n][kk][lane][e] = W[mat][ k = kk*32 + (lane>>4)*8 + e ][ j = n*16 + (lane&15) ]
__global__ __launch_bounds__(256) void convw_kernel(const float* __restrict__ W, __bf16* __restrict__ wt, int total) {
    const int idx = blockIdx.x * 256 + threadIdx.x;
    if (idx >= total) return;
    const int mat  = idx >> 14;
    const int e    = idx & 7;
    const int lane = (idx >> 3) & 63;
    const int kk   = (idx >> 9) & 3;
    const int n    = (idx >> 11) & 7;
    const int j = n * 16 + (lane & 15);
    const int k = kk * 32 + ((lane >> 4) << 3) + e;
    wt[idx] = (__bf16)W[(size_t)mat * 16384 + k * HD + j];
}

extern "C" void kernel_launch(void* const* d_in, const int* in_sizes, int n_in,
                              void* d_out, int out_size, void* d_ws, size_t ws_size,
                              hipStream_t stream) {
    const float* scalar = (const float*)d_in[0];
    const float* ef     = (const float*)d_in[1];
    const int*   eidx   = (const int*)  d_in[2];
    const float* Cn     = (const float*)d_in[3];
    const float* cs     = (const float*)d_in[4];
    const int*   bidx   = (const int*)  d_in[5];
    const float* resW   = (const float*)d_in[6];
    const float* resB   = (const float*)d_in[7];
    const float* elin   = (const float*)d_in[8];

    const int N      = in_sizes[0] / HD;
    const int E      = in_sizes[1] / 16;
    const int n_res  = in_sizes[7] / (2 * HD);
    const int layers = (n_res - 3) / 6;
    const int G      = out_size / HD;
    const size_t nfeat = (size_t)N * HD;

    char* p = (char*)d_ws;
    auto alloc = [&](size_t bytes) { char* q = p; p += (bytes + 255) & ~(size_t)255; return q; };
    float*    A      = (float*)alloc(nfeat * 4);
    float*    Dc     = (float*)alloc(nfeat * 4);
    __bf16*   Bs16   = (__bf16*)alloc(nfeat * 2);
    __bf16*   Cs16   = (__bf16*)alloc(nfeat * 2);
    __bf16*   wt     = (__bf16*)alloc((size_t)n_res * 2 * 16384 * 2);
    float*    graph  = (float*)alloc((size_t)G * HD * 4);
    int*      rowptr = (int*)alloc((size_t)(N + 1) * 4);
    int*      rowcnt = (int*)alloc((size_t)N * 4);
    int*      csr_col= (int*)alloc((size_t)E * 4);
    _Float16* csr_ef = (_Float16*)alloc((size_t)E * 16 * 2);
    _Float16* elin16 = (_Float16*)alloc((size_t)layers * 16 * HD * 2);
    int*      part   = (int*)alloc(1024 * 4);

    const int* erow = eidx;
    const int* ecol = eidx + E;

    const int totW = n_res * 2 * 16384;
    convw_kernel<<<(totW + 255) / 256, 256, 0, stream>>>(resW, wt, totW);
    const int totE = layers * 16 * HD;
    elin16_kernel<<<(totE + 255) / 256, 256, 0, stream>>>(elin, elin16, totE);

    const int nchunks = (N + 1023) / 1024;
    hipMemsetAsync(rowcnt, 0, (size_t)N * 4, stream);
    hist_kernel<<<1024, 256, 0, stream>>>(erow, rowcnt, E);
    scan1_kernel<<<nchunks, 256, 0, stream>>>(rowcnt, part, N);
    scan2_kernel<<<1, 256, 0, stream>>>(part, nchunks, rowptr, N);
    scan3_kernel<<<nchunks, 256, 0, stream>>>(rowcnt, part, rowptr, N);
    hipMemsetAsync(rowcnt, 0, (size_t)N * 4, stream);
    scatter_reorder_kernel<<<1024, 256, 0, stream>>>(erow, ecol, ef, cs, rowptr, rowcnt, csr_col, csr_ef, E);

    const int gridR = (N + 127) / 128;
    const float* cur = scalar;
    for (int i = 0; i < layers; ++i) {
        const int pb = 6 * i;
        resid_dual_kernel<<<gridR, 512, 0, stream>>>(
            cur,
            wt + (size_t)pb * 32768, resB + (size_t)pb * 256,
            wt + (size_t)(pb + 1) * 32768, resB + (size_t)(pb + 1) * 256,
            Bs16, Cs16, N);
        conv_kernel<<<(N + 3) / 4, 256, 0, stream>>>(
            csr_ef, csr_col, elin16 + (size_t)i * 16 * HD, rowptr, Cs16, Cn, Dc, N);
        chain4_kernel<<<gridR, 512, 0, stream>>>(
            Dc, Bs16,
            wt + (size_t)(pb + 2) * 32768, resB + (size_t)(pb + 2) * 256,
            wt + (size_t)(pb + 3) * 32768, resB + (size_t)(pb + 3) * 256,
            wt + (size_t)(pb + 4) * 32768, resB + (size_t)(pb + 4) * 256,
            wt + (size_t)(pb + 5) * 32768, resB + (size_t)(pb + 5) * 256,
            cur, A, N);
        cur = A;
    }

    hipMemsetAsync(graph, 0, (size_t)G * HD * 4, stream);
    pool_kernel<<<(N + 255) / 256, 256, 0, stream>>>(cur, bidx, graph, N);

    const int q = 6 * layers;
    const int gridG = (G + 127) / 128;
    chain3_kernel<<<gridG, 512, 0, stream>>>(
        graph,
        wt + (size_t)q * 32768, resB + (size_t)q * 256,
        wt + (size_t)(q + 1) * 32768, resB + (size_t)(q + 1) * 256,
        wt + (size_t)(q + 2) * 32768, resB + (size_t)(q + 2) * 256,
        (float*)d_out, G);
}

// Round 15
// 720.234 us; speedup vs baseline: 1.6600x; 1.6600x over previous
//
#include <hip/hip_runtime.h>
#include <hip/hip_bf16.h>
#include <cstdint>
#include <cstddef>

#define HD 128
#define R0OFF 0
#define R1OFF 8192
#define DATA_LDS 16384

typedef __bf16    bf16x8 __attribute__((ext_vector_type(8)));
typedef float     f32x4  __attribute__((ext_vector_type(4)));
typedef float     f32x16 __attribute__((ext_vector_type(16)));
typedef _Float16  h2     __attribute__((ext_vector_type(2)));
typedef _Float16  h8     __attribute__((ext_vector_type(8)));

#if defined(__has_builtin)
#if __has_builtin(__builtin_amdgcn_fdot2)
#define HAVE_FDOT2 1
#endif
#if __has_builtin(__builtin_amdgcn_rcpf)
#define HAVE_RCPF 1
#endif
#endif

__device__ __forceinline__ float fdot2f(h2 a, h2 b, float c) {
#ifdef HAVE_FDOT2
    return __builtin_amdgcn_fdot2(a, b, c, false);
#else
    return c + (float)a[0]*(float)b[0] + (float)a[1]*(float)b[1];
#endif
}

// fast silu: v * v_rcp(1+e^-v)
__device__ __forceinline__ float silu_f(float v) {
#ifdef HAVE_RCPF
    return v * __builtin_amdgcn_rcpf(1.f + __expf(-v));
#else
    return v / (1.f + __expf(-v));
#endif
}

// Swizzled LDS byte offset (data regions): chunk ^= (r&15) -> 2-way max on 32-row column reads
__device__ __forceinline__ int swz(int r, int byteInRow) {
    int chunk = (byteInRow >> 4) ^ (r & 15);
    return r * 256 + (chunk << 4) + (byteInRow & 15);
}

// C/D row-in-tile for mfma_f32_32x32x16_bf16
__device__ __forceinline__ int crow32(int r, int lane) {
    return (r & 3) + 8 * (r >> 2) + 4 * (lane >> 5);
}

// stage 32 rows of f32 x as bf16 into region R0 (256 threads)
__device__ __forceinline__ void stage_x32(const float* __restrict__ x, char* lds,
                                          int r0, int nrows, int tid) {
    const int q = tid & 15;
    const int r = tid >> 4;          // 0..15
    #pragma unroll
    for (int rr = 0; rr < 2; ++rr) {
        const int row = r + rr * 16;
        const int gr = r0 + row;
        float4 a = {0,0,0,0}, b = {0,0,0,0};
        if (gr < nrows) {
            const float4* p = (const float4*)(x + (size_t)gr * HD + q * 8);
            a = p[0]; b = p[1];
        }
        bf16x8 v;
        v[0]=(__bf16)a.x; v[1]=(__bf16)a.y; v[2]=(__bf16)a.z; v[3]=(__bf16)a.w;
        v[4]=(__bf16)b.x; v[5]=(__bf16)b.y; v[6]=(__bf16)b.z; v[7]=(__bf16)b.w;
        *(bf16x8*)(lds + swz(row, q * 16)) = v;
    }
}

// one mm pass: acc = (data[roff][32x128] @ W) coltile ct + bias. A-frags from LDS;
// W-frags from global in pre-arranged fragment layout (L1/L2-broadcast across blocks).
__device__ __forceinline__ void mm_pass_g(const char* lds, int roff,
                                          const __bf16* __restrict__ wf,
                                          const float* __restrict__ bias,
                                          int ct, int lane,
                                          f32x16& accA, f32x16& accB) {
    const int rowA = lane & 31;
    const int kb   = (lane >> 5) * 16;
    const __bf16* wbase = wf + ct * 4096 + lane * 8;
    bf16x8 wfr[8];
    #pragma unroll
    for (int s = 0; s < 8; ++s)
        wfr[s] = *(const bf16x8*)(wbase + s * 512);
    const float bv = bias[ct * 32 + (lane & 31)];
    #pragma unroll
    for (int r = 0; r < 16; ++r) { accA[r] = bv; accB[r] = 0.f; }
    #pragma unroll
    for (int s = 0; s < 8; s += 2) {
        const bf16x8 a0 = *(const bf16x8*)(lds + roff + swz(rowA, s * 32 + kb));
        accA = __builtin_amdgcn_mfma_f32_32x32x16_bf16(a0, wfr[s], accA, 0, 0, 0);
        const bf16x8 a1 = *(const bf16x8*)(lds + roff + swz(rowA, (s + 1) * 32 + kb));
        accB = __builtin_amdgcn_mfma_f32_32x32x16_bf16(a1, wfr[s + 1], accB, 0, 0, 0);
    }
}

__device__ __forceinline__ void write_h32(char* lds, int roff, const f32x16& aA, const f32x16& aB,
                                          int ct, int lane) {
    const int colb = (ct * 32 + (lane & 31)) * 2;
    #pragma unroll
    for (int r = 0; r < 16; ++r)
        *(__bf16*)(lds + roff + swz(crow32(r, lane), colb)) =
            (__bf16)silu_f(aA[r] + aB[r]);
}

__device__ __forceinline__ void restage32(char* lds, int roff, const float carry[16],
                                          int ct, int lane) {
    const int colb = (ct * 32 + (lane & 31)) * 2;
    #pragma unroll
    for (int r = 0; r < 16; ++r)
        *(__bf16*)(lds + roff + swz(crow32(r, lane), colb)) = (__bf16)carry[r];
}

// ---- dual residual: out1 = bf16(x + mlpA(x)), out2 = bf16(x + mlpB(x)) ----
__global__ __launch_bounds__(256, 4) void resid_dual_kernel(
    const float* __restrict__ x,
    const __bf16* __restrict__ wtA, const float* __restrict__ bA,
    const __bf16* __restrict__ wtB, const float* __restrict__ bB,
    __bf16* __restrict__ out1, __bf16* __restrict__ out2, int nrows)
{
    __shared__ char lds[DATA_LDS];
    const int tid = threadIdx.x, lane = tid & 63, ct = tid >> 6;
    const int r0 = blockIdx.x * 32;
    const int colg = ct * 32 + (lane & 31);

    stage_x32(x, lds, r0, nrows, tid);
    f32x16 accA, accB;
    float xe[16];
    #pragma unroll
    for (int r = 0; r < 16; ++r) {
        const int gr = r0 + crow32(r, lane);
        xe[r] = (gr < nrows) ? x[(size_t)gr * HD + colg] : 0.f;
    }
    __syncthreads();

    // A0: R0(x) -> h in R1
    mm_pass_g(lds, R0OFF, wtA, bA, ct, lane, accA, accB);
    write_h32(lds, R1OFF, accA, accB, ct, lane);
    __syncthreads();
    // A1: R1 -> out1 (global)
    mm_pass_g(lds, R1OFF, wtA + 16384, bA + HD, ct, lane, accA, accB);
    #pragma unroll
    for (int r = 0; r < 16; ++r) {
        const int gr = r0 + crow32(r, lane);
        if (gr < nrows)
            out1[(size_t)gr * HD + colg] = (__bf16)(xe[r] + silu_f(accA[r] + accB[r]));
    }
    __syncthreads();      // WAR: B0 overwrites R1
    // B0: R0(x, untouched) -> h in R1
    mm_pass_g(lds, R0OFF, wtB, bB, ct, lane, accA, accB);
    write_h32(lds, R1OFF, accA, accB, ct, lane);
    __syncthreads();
    // B1: R1 -> out2
    mm_pass_g(lds, R1OFF, wtB + 16384, bB + HD, ct, lane, accA, accB);
    #pragma unroll
    for (int r = 0; r < 16; ++r) {
        const int gr = r0 + crow32(r, lane);
        if (gr < nrows)
            out2[(size_t)gr * HD + colg] = (__bf16)(xe[r] + silu_f(accA[r] + accB[r]));
    }
}

// ---- fused 4-block chain: y = post + R_D(R_C(mid ⊙ R_B(R_A(x)))) ----
__global__ __launch_bounds__(256, 4) void chain4_kernel(
    const float* __restrict__ x, const __bf16* __restrict__ mid,
    const __bf16* __restrict__ wA, const float* __restrict__ bA,
    const __bf16* __restrict__ wB, const float* __restrict__ bB,
    const __bf16* __restrict__ wC, const float* __restrict__ bC,
    const __bf16* __restrict__ wD, const float* __restrict__ bD,
    const float* __restrict__ post, float* __restrict__ y, int nrows)
{
    __shared__ char lds[DATA_LDS];
    const int tid = threadIdx.x, lane = tid & 63, ct = tid >> 6;
    const int r0 = blockIdx.x * 32;
    const int colg = ct * 32 + (lane & 31);

    stage_x32(x, lds, r0, nrows, tid);
    f32x16 accA, accB;
    float carry[16];
    #pragma unroll
    for (int r = 0; r < 16; ++r) {
        const int gr = r0 + crow32(r, lane);
        carry[r] = (gr < nrows) ? x[(size_t)gr * HD + colg] : 0.f;
    }
    __syncthreads();

    // A0: R0 -> R1
    mm_pass_g(lds, R0OFF, wA, bA, ct, lane, accA, accB);
    write_h32(lds, R1OFF, accA, accB, ct, lane);
    __syncthreads();
    // A1: R1 -> carry; restage carry -> R0
    mm_pass_g(lds, R1OFF, wA + 16384, bA + HD, ct, lane, accA, accB);
    #pragma unroll
    for (int r = 0; r < 16; ++r) carry[r] += silu_f(accA[r] + accB[r]);
    restage32(lds, R0OFF, carry, ct, lane);
    __syncthreads();
    // B0: R0 -> R1
    mm_pass_g(lds, R0OFF, wB, bB, ct, lane, accA, accB);
    write_h32(lds, R1OFF, accA, accB, ct, lane);
    __syncthreads();
    // B1: R1 -> carry (+ mid); restage -> R0
    mm_pass_g(lds, R1OFF, wB + 16384, bB + HD, ct, lane, accA, accB);
    #pragma unroll
    for (int r = 0; r < 16; ++r) {
        const int gr = r0 + crow32(r, lane);
        const float m = (gr < nrows) ? (float)mid[(size_t)gr * HD + colg] : 0.f;
        carry[r] = (carry[r] + silu_f(accA[r] + accB[r])) * m;
    }
    restage32(lds, R0OFF, carry, ct, lane);
    __syncthreads();
    // C0: R0 -> R1
    mm_pass_g(lds, R0OFF, wC, bC, ct, lane, accA, accB);
    write_h32(lds, R1OFF, accA, accB, ct, lane);
    __syncthreads();
    // C1: R1 -> carry; restage -> R0
    mm_pass_g(lds, R1OFF, wC + 16384, bC + HD, ct, lane, accA, accB);
    #pragma unroll
    for (int r = 0; r < 16; ++r) carry[r] += silu_f(accA[r] + accB[r]);
    restage32(lds, R0OFF, carry, ct, lane);
    __syncthreads();
    // D0: R0 -> R1
    mm_pass_g(lds, R0OFF, wD, bD, ct, lane, accA, accB);
    write_h32(lds, R1OFF, accA, accB, ct, lane);
    __syncthreads();
    // D1: R1 -> epilogue
    mm_pass_g(lds, R1OFF, wD + 16384, bD + HD, ct, lane, accA, accB);
    #pragma unroll
    for (int r = 0; r < 16; ++r) {
        const int gr = r0 + crow32(r, lane);
        if (gr < nrows)
            y[(size_t)gr * HD + colg] =
                carry[r] + silu_f(accA[r] + accB[r]) + post[(size_t)gr * HD + colg];
    }
}

// ---- fused 3-block graph chain: out = R_C(R_B(R_A(x))) ----
__global__ __launch_bounds__(256, 4) void chain3_kernel(
    const float* __restrict__ x,
    const __bf16* __restrict__ wA, const float* __restrict__ bA,
    const __bf16* __restrict__ wB, const float* __restrict__ bB,
    const __bf16* __restrict__ wC, const float* __restrict__ bC,
    float* __restrict__ y, int nrows)
{
    __shared__ char lds[DATA_LDS];
    const int tid = threadIdx.x, lane = tid & 63, ct = tid >> 6;
    const int r0 = blockIdx.x * 32;
    const int colg = ct * 32 + (lane & 31);

    stage_x32(x, lds, r0, nrows, tid);
    f32x16 accA, accB;
    float carry[16];
    #pragma unroll
    for (int r = 0; r < 16; ++r) {
        const int gr = r0 + crow32(r, lane);
        carry[r] = (gr < nrows) ? x[(size_t)gr * HD + colg] : 0.f;
    }
    __syncthreads();

    mm_pass_g(lds, R0OFF, wA, bA, ct, lane, accA, accB);
    write_h32(lds, R1OFF, accA, accB, ct, lane);
    __syncthreads();
    mm_pass_g(lds, R1OFF, wA + 16384, bA + HD, ct, lane, accA, accB);
    #pragma unroll
    for (int r = 0; r < 16; ++r) carry[r] += silu_f(accA[r] + accB[r]);
    restage32(lds, R0OFF, carry, ct, lane);
    __syncthreads();
    mm_pass_g(lds, R0OFF, wB, bB, ct, lane, accA, accB);
    write_h32(lds, R1OFF, accA, accB, ct, lane);
    __syncthreads();
    mm_pass_g(lds, R1OFF, wB + 16384, bB + HD, ct, lane, accA, accB);
    #pragma unroll
    for (int r = 0; r < 16; ++r) carry[r] += silu_f(accA[r] + accB[r]);
    restage32(lds, R0OFF, carry, ct, lane);
    __syncthreads();
    mm_pass_g(lds, R0OFF, wC, bC, ct, lane, accA, accB);
    write_h32(lds, R1OFF, accA, accB, ct, lane);
    __syncthreads();
    mm_pass_g(lds, R1OFF, wC + 16384, bC + HD, ct, lane, accA, accB);
    #pragma unroll
    for (int r = 0; r < 16; ++r) {
        const int gr = r0 + crow32(r, lane);
        if (gr < nrows)
            y[(size_t)gr * HD + colg] = carry[r] + silu_f(accA[r] + accB[r]);
    }
}

// ---- CSR build ----
__global__ __launch_bounds__(256) void hist_kernel(const int* __restrict__ erow, int* __restrict__ cnt, int E) {
    int i = blockIdx.x * blockDim.x + threadIdx.x;
    const int stride = gridDim.x * blockDim.x;
    for (; i < E; i += stride) atomicAdd(&cnt[erow[i]], 1);
}

__global__ __launch_bounds__(256) void scan1_kernel(const int* __restrict__ cnt, int* __restrict__ part, int n) {
    __shared__ int red[256];
    const int base = blockIdx.x * 1024;
    int s = 0;
    for (int i = threadIdx.x; i < 1024; i += 256) {
        const int idx = base + i;
        s += (idx < n) ? cnt[idx] : 0;
    }
    red[threadIdx.x] = s; __syncthreads();
    for (int o = 128; o > 0; o >>= 1) {
        if (threadIdx.x < o) red[threadIdx.x] += red[threadIdx.x + o];
        __syncthreads();
    }
    if (threadIdx.x == 0) part[blockIdx.x] = red[0];
}

__global__ __launch_bounds__(256) void scan2_kernel(int* __restrict__ part, int nb,
                                                    int* __restrict__ rowptr, int n) {
    __shared__ int sh[257];
    const int tid = threadIdx.x;
    int a[4]; int s = 0;
    #pragma unroll
    for (int q = 0; q < 4; ++q) {
        const int i = tid*4 + q;
        a[q] = (i < nb) ? part[i] : 0;
        s += a[q];
    }
    sh[tid + 1] = s; __syncthreads();
    if (tid == 0) {
        sh[0] = 0;
        int run = 0;
        for (int i = 1; i <= 256; ++i) { run += sh[i]; sh[i] = run; }
    }
    __syncthreads();
    int off = sh[tid];
    #pragma unroll
    for (int q = 0; q < 4; ++q) {
        const int i = tid*4 + q;
        if (i < nb) part[i] = off;
        off += a[q];
    }
    if (tid == 255) rowptr[n] = off;
}

__global__ __launch_bounds__(256) void scan3_kernel(const int* __restrict__ cnt, const int* __restrict__ part,
                                                    int* __restrict__ rowptr, int n) {
    __shared__ int sc[257];
    const int base = blockIdx.x * 1024;
    const int i0 = base + threadIdx.x * 4;
    int v[4]; int s = 0;
    #pragma unroll
    for (int q = 0; q < 4; ++q) {
        const int idx = i0 + q;
        v[q] = (idx < n) ? cnt[idx] : 0;
        s += v[q];
    }
    sc[threadIdx.x + 1] = s; __syncthreads();
    if (threadIdx.x == 0) {
        int run = 0;
        for (int i = 0; i < 256; ++i) { const int t = sc[i + 1]; sc[i + 1] = run; run += t; }
    }
    __syncthreads();
    int off = part[blockIdx.x] + sc[threadIdx.x + 1];
    #pragma unroll
    for (int q = 0; q < 4; ++q) {
        const int idx = i0 + q;
        if (idx < n) rowptr[idx] = off;
        off += v[q];
    }
}

// scatter + reorder fused: csr_col[p] = ecol[i], csr_ef[p] = fp16(ef[i] * cs[i])
__global__ __launch_bounds__(256) void scatter_reorder_kernel(
    const int* __restrict__ erow, const int* __restrict__ ecol,
    const float* __restrict__ ef, const float* __restrict__ cs,
    const int* __restrict__ rowptr, int* __restrict__ cursor,
    int* __restrict__ csr_col, _Float16* __restrict__ csr_ef, int E)
{
    int i = blockIdx.x * blockDim.x + threadIdx.x;
    const int stride = gridDim.x * blockDim.x;
    for (; i < E; i += stride) {
        const int r = erow[i];
        const int p = rowptr[r] + atomicAdd(&cursor[r], 1);
        csr_col[p] = ecol[i];
        const float c = cs[i];
        const float4* ep = (const float4*)(ef + (size_t)i * 16);
        const float4 e0 = ep[0], e1 = ep[1], e2 = ep[2], e3 = ep[3];
        h8 v0, v1;
        v0[0]=(_Float16)(e0.x*c); v0[1]=(_Float16)(e0.y*c); v0[2]=(_Float16)(e0.z*c); v0[3]=(_Float16)(e0.w*c);
        v0[4]=(_Float16)(e1.x*c); v0[5]=(_Float16)(e1.y*c); v0[6]=(_Float16)(e1.z*c); v0[7]=(_Float16)(e1.w*c);
        v1[0]=(_Float16)(e2.x*c); v1[1]=(_Float16)(e2.y*c); v1[2]=(_Float16)(e2.z*c); v1[3]=(_Float16)(e2.w*c);
        v1[4]=(_Float16)(e3.x*c); v1[5]=(_Float16)(e3.y*c); v1[6]=(_Float16)(e3.z*c); v1[7]=(_Float16)(e3.w*c);
        h8* dst = (h8*)(csr_ef + (size_t)p * 16);
        dst[0] = v0; dst[1] = v1;
    }
}

// elin f32 [16][128] -> fp16 (per layer)
__global__ __launch_bounds__(256) void elin16_kernel(const float* __restrict__ elin,
                                                     _Float16* __restrict__ out, int total) {
    const int i = blockIdx.x * 256 + threadIdx.x;
    if (i < total) out[i] = (_Float16)elin[i];
}

__device__ __forceinline__ float bfu_lo(uint32_t u) { return __uint_as_float(u << 16); }
__device__ __forceinline__ float bfu_hi(uint32_t u) { return __uint_as_float(u & 0xffff0000u); }

__device__ __forceinline__ void edge_dot(const h8 a0, const h8 a1,
                                         const h2 w0[8], const h2 w1[8],
                                         float& f0, float& f1) {
    #pragma unroll
    for (int kk = 0; kk < 4; ++kk) {
        h2 p = {a0[2*kk], a0[2*kk+1]};
        f0 = fdot2f(p, w0[kk], f0);
        f1 = fdot2f(p, w1[kk], f1);
    }
    #pragma unroll
    for (int kk = 0; kk < 4; ++kk) {
        h2 p = {a1[2*kk], a1[2*kk+1]};
        f0 = fdot2f(p, w0[4+kk], f0);
        f1 = fdot2f(p, w1[4+kk], f1);
    }
}

// ---- CSR gather conv, wave-per-node: lane handles cols (2l, 2l+1); unroll-8 gathers ----
__global__ __launch_bounds__(256) void conv_kernel(
    const _Float16* __restrict__ csr_ef, const int* __restrict__ csr_col,
    const _Float16* __restrict__ elin16, const int* __restrict__ rowptr,
    const __bf16* __restrict__ sdst, const float* __restrict__ Cn,
    float* __restrict__ conv, int nnodes)
{
    const int wv   = __builtin_amdgcn_readfirstlane(threadIdx.x >> 6);
    const int lane = threadIdx.x & 63;
    const int v = blockIdx.x * 4 + wv;
    if (v >= nnodes) return;
    const int j0 = lane * 2;

    h2 w0[8], w1[8];
    #pragma unroll
    for (int kk = 0; kk < 8; ++kk) {
        w0[kk][0] = elin16[(2*kk)   * HD + j0];
        w0[kk][1] = elin16[(2*kk+1) * HD + j0];
        w1[kk][0] = elin16[(2*kk)   * HD + j0 + 1];
        w1[kk][1] = elin16[(2*kk+1) * HD + j0 + 1];
    }

    const uint16_t* sd = (const uint16_t*)sdst;
    const int beg = rowptr[v], end = rowptr[v + 1];
    float acc0 = 0.f, acc1 = 0.f;
    int t = beg;
    for (; t + 8 <= end; t += 8) {
        int c[8];
        #pragma unroll
        for (int q = 0; q < 8; ++q) c[q] = csr_col[t + q];
        uint32_t u[8];
        #pragma unroll
        for (int q = 0; q < 8; ++q)
            u[q] = *(const uint32_t*)(sd + (size_t)c[q] * HD + j0);
        #pragma unroll
        for (int q = 0; q < 8; ++q) {
            const h8* ep = (const h8*)(csr_ef + (size_t)(t + q) * 16);
            const h8 a0 = ep[0], a1 = ep[1];
            float f0 = 0.f, f1 = 0.f;
            edge_dot(a0, a1, w0, w1, f0, f1);
            acc0 = fmaf(bfu_lo(u[q]), f0, acc0);
            acc1 = fmaf(bfu_hi(u[q]), f1, acc1);
        }
    }
    for (; t + 2 <= end; t += 2) {
        int c[2];
        c[0] = csr_col[t]; c[1] = csr_col[t + 1];
        uint32_t u[2];
        u[0] = *(const uint32_t*)(sd + (size_t)c[0] * HD + j0);
        u[1] = *(const uint32_t*)(sd + (size_t)c[1] * HD + j0);
        #pragma unroll
        for (int q = 0; q < 2; ++q) {
            const h8* ep = (const h8*)(csr_ef + (size_t)(t + q) * 16);
            const h8 a0 = ep[0], a1 = ep[1];
            float f0 = 0.f, f1 = 0.f;
            edge_dot(a0, a1, w0, w1, f0, f1);
            acc0 = fmaf(bfu_lo(u[q]), f0, acc0);
            acc1 = fmaf(bfu_hi(u[q]), f1, acc1);
        }
    }
    if (t < end) {
        const int c = csr_col[t];
        const uint32_t u = *(const uint32_t*)(sd + (size_t)c * HD + j0);
        const h8* ep = (const h8*)(csr_ef + (size_t)t * 16);
        const h8 a0 = ep[0], a1 = ep[1];
        float f0 = 0.f, f1 = 0.f;
        edge_dot(a0, a1, w0, w1, f0, f1);
        acc0 = fmaf(bfu_lo(u), f0, acc0);
        acc1 = fmaf(bfu_hi(u), f1, acc1);
    }
    const float cn = Cn[v];
    float2 out = {acc0 * cn, acc1 * cn};
    *(float2*)(conv + (size_t)v * HD + j0) = out;
}

// sorted segment-sum pooling
__global__ __launch_bounds__(256) void pool_kernel(
    const float* __restrict__ s, const int* __restrict__ bidx,
    float* __restrict__ g, int n)
{
    const int slot = threadIdx.x >> 5;
    const int jc   = (threadIdx.x & 31) * 4;
    const int base = blockIdx.x * 256;
    if (base >= n) return;
    const int end = (base + 256 < n) ? base + 256 : n;
    float4 acc = {0,0,0,0};
    int cur = -1;
    for (int i = base + slot; i < end; i += 8) {
        const int b = bidx[i];
        if (b != cur) {
            if (cur >= 0) {
                atomicAdd(g + (size_t)cur*HD + jc + 0, acc.x);
                atomicAdd(g + (size_t)cur*HD + jc + 1, acc.y);
                atomicAdd(g + (size_t)cur*HD + jc + 2, acc.z);
                atomicAdd(g + (size_t)cur*HD + jc + 3, acc.w);
            }
            acc = {0,0,0,0};
            cur = b;
        }
        const float4 v = *(const float4*)(s + (size_t)i*HD + jc);
        acc.x += v.x; acc.y += v.y; acc.z += v.z; acc.w += v.w;
    }
    if (cur >= 0) {
        atomicAdd(g + (size_t)cur*HD + jc + 0, acc.x);
        atomicAdd(g + (size_t)cur*HD + jc + 1, acc.y);
        atomicAdd(g + (size_t)cur*HD + jc + 2, acc.z);
        atomicAdd(g + (size_t)cur*HD + jc + 3, acc.w);
    }
}

// W -> per-lane MFMA fragment layout (bf16):
// wt[mat][ct][s][lane][e] = W[mat][ k = s*16 + (lane>>5)*8 + e ][ j = ct*32 + (lane&31) ]
__global__ __launch_bounds__(256) void convw_kernel(const float* __restrict__ W, __bf16* __restrict__ wt, int total) {
    const int idx = blockIdx.x * 256 + threadIdx.x;
    if (idx >= total) return;
    const int mat  = idx >> 14;
    const int e    = idx & 7;
    const int lane = (idx >> 3) & 63;
    const int s    = (idx >> 9) & 7;
    const int ct   = (idx >> 12) & 3;
    const int j = ct * 32 + (lane & 31);
    const int k = s * 16 + ((lane >> 5) << 3) + e;
    wt[idx] = (__bf16)W[(size_t)mat * 16384 + k * HD + j];
}

extern "C" void kernel_launch(void* const* d_in, const int* in_sizes, int n_in,
                              void* d_out, int out_size, void* d_ws, size_t ws_size,
                              hipStream_t stream) {
    const float* scalar = (const float*)d_in[0];
    const float* ef     = (const float*)d_in[1];
    const int*   eidx   = (const int*)  d_in[2];
    const float* Cn     = (const float*)d_in[3];
    const float* cs     = (const float*)d_in[4];
    const int*   bidx   = (const int*)  d_in[5];
    const float* resW   = (const float*)d_in[6];
    const float* resB   = (const float*)d_in[7];
    const float* elin   = (const float*)d_in[8];

    const int N      = in_sizes[0] / HD;
    const int E      = in_sizes[1] / 16;
    const int n_res  = in_sizes[7] / (2 * HD);
    const int layers = (n_res - 3) / 6;
    const int G      = out_size / HD;
    const size_t nfeat = (size_t)N * HD;

    char* p = (char*)d_ws;
    auto alloc = [&](size_t bytes) { char* q = p; p += (bytes + 255) & ~(size_t)255; return q; };
    float*    A      = (float*)alloc(nfeat * 4);
    float*    Dc     = (float*)alloc(nfeat * 4);
    __bf16*   Bs16   = (__bf16*)alloc(nfeat * 2);
    __bf16*   Cs16   = (__bf16*)alloc(nfeat * 2);
    __bf16*   wt     = (__bf16*)alloc((size_t)n_res * 2 * 16384 * 2);
    float*    graph  = (float*)alloc((size_t)G * HD * 4);
    int*      rowptr = (int*)alloc((size_t)(N + 1) * 4);
    int*      rowcnt = (int*)alloc((size_t)N * 4);
    int*      csr_col= (int*)alloc((size_t)E * 4);
    _Float16* csr_ef = (_Float16*)alloc((size_t)E * 16 * 2);
    _Float16* elin16 = (_Float16*)alloc((size_t)layers * 16 * HD * 2);
    int*      part   = (int*)alloc(1024 * 4);

    const int* erow = eidx;
    const int* ecol = eidx + E;

    const int totW = n_res * 2 * 16384;
    convw_kernel<<<(totW + 255) / 256, 256, 0, stream>>>(resW, wt, totW);
    const int totE = layers * 16 * HD;
    elin16_kernel<<<(totE + 255) / 256, 256, 0, stream>>>(elin, elin16, totE);

    const int nchunks = (N + 1023) / 1024;
    hipMemsetAsync(rowcnt, 0, (size_t)N * 4, stream);
    hist_kernel<<<1024, 256, 0, stream>>>(erow, rowcnt, E);
    scan1_kernel<<<nchunks, 256, 0, stream>>>(rowcnt, part, N);
    scan2_kernel<<<1, 256, 0, stream>>>(part, nchunks, rowptr, N);
    scan3_kernel<<<nchunks, 256, 0, stream>>>(rowcnt, part, rowptr, N);
    hipMemsetAsync(rowcnt, 0, (size_t)N * 4, stream);
    scatter_reorder_kernel<<<1024, 256, 0, stream>>>(erow, ecol, ef, cs, rowptr, rowcnt, csr_col, csr_ef, E);

    const int gridR = (N + 31) / 32;
    const float* cur = scalar;
    for (int i = 0; i < layers; ++i) {
        const int pb = 6 * i;
        resid_dual_kernel<<<gridR, 256, 0, stream>>>(
            cur,
            wt + (size_t)pb * 32768, resB + (size_t)pb * 256,
            wt + (size_t)(pb + 1) * 32768, resB + (size_t)(pb + 1) * 256,
            Bs16, Cs16, N);
        conv_kernel<<<(N + 3) / 4, 256, 0, stream>>>(
            csr_ef, csr_col, elin16 + (size_t)i * 16 * HD, rowptr, Cs16, Cn, Dc, N);
        chain4_kernel<<<gridR, 256, 0, stream>>>(
            Dc, Bs16,
            wt + (size_t)(pb + 2) * 32768, resB + (size_t)(pb + 2) * 256,
            wt + (size_t)(pb + 3) * 32768, resB + (size_t)(pb + 3) * 256,
            wt + (size_t)(pb + 4) * 32768, resB + (size_t)(pb + 4) * 256,
            wt + (size_t)(pb + 5) * 32768, resB + (size_t)(pb + 5) * 256,
            cur, A, N);
        cur = A;
    }

    hipMemsetAsync(graph, 0, (size_t)G * HD * 4, stream);
    pool_kernel<<<(N + 255) / 256, 256, 0, stream>>>(cur, bidx, graph, N);

    const int q = 6 * layers;
    const int gridG = (G + 31) / 32;
    chain3_kernel<<<gridG, 256, 0, stream>>>(
        graph,
        wt + (size_t)q * 32768, resB + (size_t)q * 256,
        wt + (size_t)(q + 1) * 32768, resB + (size_t)(q + 1) * 256,
        wt + (size_t)(q + 2) * 32768, resB + (size_t)(q + 2) * 256,
        (float*)d_out, G);
}